// Round 2
// baseline (164.352 us; speedup 1.0000x reference)
//
#include <hip/hip_runtime.h>
#include <hip/hip_bf16.h>
#include <math.h>

#define B_ 4
#define S_ 2048
#define E_ 1024
#define H_ 64
#define NQT 32          // S/64 q-tiles
#define SPLITS 8
#define TPS 4           // 64-key tiles per split (256 keys/split)
#define SENT (-1.25e8f) // masked-logit sentinel (= -1e9 * 0.125)

typedef short bf16x8 __attribute__((ext_vector_type(8)));
typedef float f32x4 __attribute__((ext_vector_type(4)));
typedef unsigned short U16;
typedef U16 u16x8 __attribute__((ext_vector_type(8)));
typedef U16 u16x4 __attribute__((ext_vector_type(4)));

__device__ __forceinline__ U16 f2bf(float f){
    unsigned u = __builtin_bit_cast(unsigned, f);
    u += 0x7fffu + ((u >> 16) & 1u);          // RNE
    return (U16)(u >> 16);
}
__device__ __forceinline__ float bf2f(U16 h){
    return __builtin_bit_cast(float, ((unsigned)h) << 16);
}
#define MFMA16(a,b,c) __builtin_amdgcn_mfma_f32_16x16x32_bf16((a),(b),(c),0,0,0)

typedef const __attribute__((address_space(1))) void GvPtr;
typedef __attribute__((address_space(3))) void LdsPtr;
__device__ __forceinline__ void gload_lds16(const void* g, void* l){
    // async 16B/lane global->LDS; LDS dest = wave-uniform base + lane*16
    __builtin_amdgcn_global_load_lds((GvPtr*)g, (LdsPtr*)l, 16, 0, 0);
}

// ---------------------------------------------------------------------------
// Kernel 0: split W (3 comps, fp32) into hi/lo bf16 pair arrays.
// ---------------------------------------------------------------------------
__global__ __launch_bounds__(256) void prep_w(
    const float* __restrict__ Wq, const float* __restrict__ Wk,
    const float* __restrict__ Wv, U16* __restrict__ Whi, U16* __restrict__ Wlo)
{
    int i4 = (blockIdx.x*256 + threadIdx.x) * 4;     // < 3*65536
    int c = i4 >> 16, rem = i4 & 65535;
    const float* src = (c==0) ? Wq : (c==1) ? Wk : Wv;
    float4 v = *(const float4*)(src + rem);
    float a[4] = {v.x, v.y, v.z, v.w};
    u16x4 hv, lv;
    #pragma unroll
    for (int j=0;j<4;j++){ U16 h = f2bf(a[j]); hv[j]=h; lv[j]=f2bf(a[j]-bf2f(h)); }
    *(u16x4*)(Whi + i4) = hv;
    *(u16x4*)(Wlo + i4) = lv;
}

// ---------------------------------------------------------------------------
// Kernel 1: fused QKV projection. 256 blocks x 32 rows; per-wave n-slice of 16
// h-cols (wave wv -> h = wv*16..+15). W frags read直接 from L2 (bf16 hi/lo),
// x staged hi/lo in double-buffered LDS (1 barrier/iter). 36 MFMA/wave/iter.
// ---------------------------------------------------------------------------
__global__ __launch_bounds__(256) void qkv_kernel(
    const float* __restrict__ x, const U16* __restrict__ Whi_g,
    const U16* __restrict__ Wlo_g,
    U16* __restrict__ Qhi, U16* __restrict__ Qlo,
    U16* __restrict__ Khi, U16* __restrict__ Klo, U16* __restrict__ Vt)
{
    __shared__ __align__(16) U16 Ah[2][32*64], Al[2][32*64];
    const int m0 = blockIdx.x * 32;
    const int tid = threadIdx.x, lane = tid & 63, wv = tid >> 6;
    const int l15 = lane & 15, quad = lane >> 4;
    const int arow = tid >> 3, ag = tid & 7;     // 32 rows x 8 groups of 8

    f32x4 acc[3][2];
    #pragma unroll
    for (int c=0;c<3;c++)
    #pragma unroll
    for (int mt=0;mt<2;mt++) acc[c][mt] = f32x4{0.f,0.f,0.f,0.f};

    // stage k0=0 into buf 0
    {
        const float* xs = x + (size_t)(m0 + arow)*E_ + ag*8;
        float4 xa = ((const float4*)xs)[0], xb = ((const float4*)xs)[1];
        float vv[8] = {xa.x,xa.y,xa.z,xa.w,xb.x,xb.y,xb.z,xb.w};
        u16x8 hv, lv;
        #pragma unroll
        for (int j=0;j<8;j++){ U16 h = f2bf(vv[j]); hv[j]=h; lv[j]=f2bf(vv[j]-bf2f(h)); }
        ((u16x8*)Ah[0])[arow*8 + ag] = hv;
        ((u16x8*)Al[0])[arow*8 + ag] = lv;
    }
    __syncthreads();

    int p = 0;
    for (int k0 = 0; k0 < E_; k0 += 64) {
        float4 xa, xb;
        const bool have = (k0 + 64 < E_);
        if (have) {
            const float* xs = x + (size_t)(m0 + arow)*E_ + k0 + 64 + ag*8;
            xa = ((const float4*)xs)[0]; xb = ((const float4*)xs)[1];
        }
        // W fragments direct from global (L2-resident), n-row = wv*16+l15
        bf16x8 bh[3][2], bl[3][2];
        #pragma unroll
        for (int c=0;c<3;c++)
        #pragma unroll
        for (int kk=0;kk<2;kk++){
            const size_t wo = (size_t)c*65536 + (size_t)(wv*16 + l15)*E_ + k0 + kk*32 + quad*8;
            bh[c][kk] = *(const bf16x8*)(Whi_g + wo);
            bl[c][kk] = *(const bf16x8*)(Wlo_g + wo);
        }
        // compute on buf p
        #pragma unroll
        for (int kk=0;kk<2;kk++){
            #pragma unroll
            for (int mt=0;mt<2;mt++){
                const int ai = (mt*16 + l15)*8 + kk*4 + quad;
                bf16x8 ah = ((const bf16x8*)Ah[p])[ai];
                bf16x8 al = ((const bf16x8*)Al[p])[ai];
                #pragma unroll
                for (int c=0;c<3;c++){
                    acc[c][mt] = MFMA16(ah, bh[c][kk], acc[c][mt]);  // hi*hi
                    acc[c][mt] = MFMA16(ah, bl[c][kk], acc[c][mt]);  // hi*lo
                    acc[c][mt] = MFMA16(al, bh[c][kk], acc[c][mt]);  // lo*hi
                }
            }
        }
        // write prefetched x into buf p^1
        if (have) {
            float vv[8] = {xa.x,xa.y,xa.z,xa.w,xb.x,xb.y,xb.z,xb.w};
            u16x8 hv, lv;
            #pragma unroll
            for (int j=0;j<8;j++){ U16 h = f2bf(vv[j]); hv[j]=h; lv[j]=f2bf(vv[j]-bf2f(h)); }
            ((u16x8*)Ah[p^1])[arow*8 + ag] = hv;
            ((u16x8*)Al[p^1])[arow*8 + ag] = lv;
        }
        __syncthreads();
        p ^= 1;
    }

    // epilogue: D lane l15 = h-col (wv*16+l15), rows = mt*16 + quad*4 + r
    const int h = wv*16 + l15;
    #pragma unroll
    for (int mt=0;mt<2;mt++){
        const int row = m0 + mt*16 + quad*4;
        #pragma unroll
        for (int r=0;r<4;r++){
            float vq = acc[0][mt][r]; U16 hq = f2bf(vq);
            Qhi[(size_t)(row+r)*H_ + h] = hq;
            Qlo[(size_t)(row+r)*H_ + h] = f2bf(vq - bf2f(hq));
            float vk = acc[1][mt][r]; U16 hk = f2bf(vk);
            Khi[(size_t)(row+r)*H_ + h] = hk;
            Klo[(size_t)(row+r)*H_ + h] = f2bf(vk - bf2f(hk));
        }
        const int b = row >> 11, s0 = row & (S_-1);
        u16x4 pk;
        #pragma unroll
        for (int r=0;r<4;r++) pk[r] = f2bf(acc[2][mt][r]);
        *(u16x4*)(Vt + ((size_t)b*H_ + h)*S_ + s0) = pk;   // V transposed [b][h][s]
    }
}

// ---------------------------------------------------------------------------
// Kernel 2: flash attention, split-K, S^T formulation (S^T = K*Q^T so each
// lane owns ONE q-row -> 4 shuffles/tile, P round-trip = b64 writes + b128
// reads). K/V staged via global_load_lds (already bf16). PV as O^T = V^T*P^T.
// ---------------------------------------------------------------------------
__global__ __launch_bounds__(256) void attn_kernel(
    const U16* __restrict__ Qhi, const U16* __restrict__ Qlo,
    const U16* __restrict__ Khi, const U16* __restrict__ Klo,
    const U16* __restrict__ Vt, const int* __restrict__ pad,
    float* __restrict__ Opart, float* __restrict__ mpart, float* __restrict__ lpart)
{
    const int qt = blockIdx.x, b = blockIdx.y, sp = blockIdx.z;
    const int t0 = sp * TPS;
    if (t0 > qt) return;
    const int t1 = min(t0 + TPS, qt + 1);

    __shared__ __align__(16) U16 KtH[64*64], KtL[64*64], Vts[64*64];
    __shared__ __align__(16) U16 Ps[4][16*80];   // per-wave P[q=16][key 64], stride 80

    const int tid = threadIdx.x, lane = tid & 63, wv = tid >> 6;
    const int l15 = lane & 15, quad = lane >> 4;

    // Q fragments as B-operand (lane l15 = q-row, k = d = quad*8+j)
    const size_t qrow = (size_t)b*S_ + qt*64 + wv*16 + l15;
    bf16x8 aqh0 = *(const bf16x8*)(Qhi + qrow*H_ + quad*8);
    bf16x8 aqh1 = *(const bf16x8*)(Qhi + qrow*H_ + 32 + quad*8);
    bf16x8 aql0 = *(const bf16x8*)(Qlo + qrow*H_ + quad*8);
    bf16x8 aql1 = *(const bf16x8*)(Qlo + qrow*H_ + 32 + quad*8);

    float m_i = -INFINITY, l_i = 0.f;
    f32x4 o[4];
    #pragma unroll
    for (int i=0;i<4;i++) o[i] = f32x4{0.f,0.f,0.f,0.f};
    const int qg = qt*64 + wv*16 + l15;          // this lane's global q row
    U16* Pw = &Ps[wv][0];

    for (int t = t0; t < t1; ++t) {
        const int kb = t * 64;
        __syncthreads();                          // protect prev-iter LDS reads
        {   // stage K hi/lo + V^T tile: each wave covers slots wv*128..+127
            const U16* kh = Khi + ((size_t)b*S_ + kb)*H_;
            const U16* kl = Klo + ((size_t)b*S_ + kb)*H_;
            #pragma unroll
            for (int ch=0; ch<2; ++ch){
                const int sb = wv*128 + ch*64;
                const int slot = sb + lane;
                gload_lds16(kh + (size_t)slot*8, (U16*)KtH + sb*8);
                gload_lds16(kl + (size_t)slot*8, (U16*)KtL + sb*8);
                const int vrow = slot >> 3, vg = slot & 7;
                gload_lds16(Vt + ((size_t)b*H_ + vrow)*S_ + kb + vg*8, (U16*)Vts + sb*8);
            }
        }
        const unsigned long long pm = __ballot(pad[(size_t)b*S_ + kb + lane] != 0);
        __syncthreads();                          // drains vmcnt -> staging done

        // --- S^T = K Q^T (hi/lo, fp32-accurate logits) ---
        f32x4 z[4];
        #pragma unroll
        for (int nt=0; nt<4; nt++){
            const int kr = (nt*16 + l15)*8;
            bf16x8 kh0 = ((const bf16x8*)KtH)[kr + quad];
            bf16x8 kh1 = ((const bf16x8*)KtH)[kr + 4 + quad];
            bf16x8 kl0 = ((const bf16x8*)KtL)[kr + quad];
            bf16x8 kl1 = ((const bf16x8*)KtL)[kr + 4 + quad];
            f32x4 zz = f32x4{0.f,0.f,0.f,0.f};
            zz = MFMA16(kh0, aqh0, zz);
            zz = MFMA16(kh1, aqh1, zz);
            zz = MFMA16(kh0, aql0, zz);
            zz = MFMA16(kh1, aql1, zz);
            zz = MFMA16(kl0, aqh0, zz);
            zz = MFMA16(kl1, aqh1, zz);
            z[nt] = zz;
        }
        // --- mask + scale; lane owns q=qg, regs span keys ---
        float rmax = -INFINITY;
        #pragma unroll
        for (int nt=0; nt<4; nt++){
            const int rel = qg - kb - nt*16 - quad*4;          // causal: r <= rel
            const unsigned mb = (unsigned)(pm >> (nt*16 + quad*4)) & 0xFu;
            #pragma unroll
            for (int r=0;r<4;r++){
                const bool ok = (r <= rel) && ((mb >> r) & 1u);
                const float v = ok ? z[nt][r]*0.125f : SENT;
                z[nt][r] = v;
                rmax = fmaxf(rmax, v);
            }
        }
        rmax = fmaxf(rmax, __shfl_xor(rmax, 16));
        rmax = fmaxf(rmax, __shfl_xor(rmax, 32));
        const float mn = fmaxf(m_i, rmax);
        const float alpha = __expf(m_i - mn);     // exp(-inf)=0 first tile
        m_i = mn;
        float rsum = 0.f;
        #pragma unroll
        for (int nt=0; nt<4; nt++)
        #pragma unroll
        for (int r=0;r<4;r++){
            const float pv = __expf(z[nt][r] - mn);
            z[nt][r] = pv;
            rsum += pv;
        }
        rsum += __shfl_xor(rsum, 16);
        rsum += __shfl_xor(rsum, 32);
        l_i = l_i*alpha + rsum;
        #pragma unroll
        for (int nt=0; nt<4; nt++)
        #pragma unroll
        for (int r=0;r<4;r++) o[nt][r] *= alpha;

        // --- P -> per-wave LDS row-major [q=l15][key] ---
        #pragma unroll
        for (int nt=0; nt<4; nt++){
            u16x4 pk;
            #pragma unroll
            for (int r=0;r<4;r++) pk[r] = f2bf(z[nt][r]);
            *(u16x4*)(Pw + l15*80 + nt*16 + quad*4) = pk;
        }
        // --- O^T += V^T P^T ---
        #pragma unroll
        for (int ks=0; ks<2; ks++){
            bf16x8 bp = *(const bf16x8*)(Pw + l15*80 + ks*32 + quad*8);
            #pragma unroll
            for (int nt=0; nt<4; nt++){
                bf16x8 av = ((const bf16x8*)Vts)[(nt*16 + l15)*8 + ks*4 + quad];
                o[nt] = MFMA16(av, bp, o[nt]);
            }
        }
    }
    // partials: row index = [b][qt][sp][q 64], cols h
    const size_t rbase = ((size_t)((b*NQT + qt)*SPLITS + sp))*64 + wv*16 + l15;
    if (quad == 0) { mpart[rbase] = m_i; lpart[rbase] = l_i; }
    #pragma unroll
    for (int nt=0; nt<4; nt++)
        *((f32x4*)(Opart + rbase*H_ + nt*16 + quad*4)) = o[nt];
}

// ---------------------------------------------------------------------------
// Kernel 3: merge split-K partials; inline mean-of-V for the rare fully-masked
// rows (reference: uniform softmax over ALL keys there).
// ---------------------------------------------------------------------------
__global__ __launch_bounds__(256) void combine_kernel(
    const float* __restrict__ Opart, const float* __restrict__ mpart,
    const float* __restrict__ lpart, const U16* __restrict__ Vt,
    float* __restrict__ out)
{
    const int idx = blockIdx.x*256 + threadIdx.x;
    const int h = idx & 63;
    const int q = (idx >> 6) & (S_-1);
    const int b = idx >> 17;
    const int qt = q >> 6, r = q & 63;
    const int ns = (qt >> 2) + 1;                 // splits that ran
    const size_t rb = ((size_t)(b*NQT + qt)*SPLITS)*64 + r;
    float M = -INFINITY;
    for (int s2=0; s2<ns; s2++) M = fmaxf(M, mpart[rb + (size_t)s2*64]);
    float res;
    if (M == SENT) {                              // no valid key: uniform over all S
        const U16* vsrc = Vt + ((size_t)b*H_ + h)*S_;
        float sm = 0.f;
        for (int s=0; s<S_; ++s) sm += bf2f(vsrc[s]);
        res = sm * (1.f/(float)S_);
    } else {
        float L = 0.f, accv = 0.f;
        for (int s2=0; s2<ns; s2++){
            const float mi = mpart[rb + (size_t)s2*64];
            const float w = __expf(mi - M);       // underflows to 0 for dead splits
            L    += w * lpart[rb + (size_t)s2*64];
            accv += w * Opart[(rb + (size_t)s2*64)*H_ + h];
        }
        res = accv / L;
    }
    out[idx] = res;
}

// ---------------------------------------------------------------------------
// Workspace: Whi 0 (384K) | Wlo 384K | Qhi 1M | Qlo 2M | Khi 3M | Klo 4M |
//            Vt 5M | Opart 6M (16M) | mpart 22M (256K) | lpart 22.25M
// ---------------------------------------------------------------------------
extern "C" void kernel_launch(void* const* d_in, const int* in_sizes, int n_in,
                              void* d_out, int out_size, void* d_ws, size_t ws_size,
                              hipStream_t stream)
{
    (void)in_sizes; (void)n_in; (void)out_size; (void)ws_size;
    const float* x  = (const float*)d_in[0];
    const int* pad  = (const int*)d_in[1];
    const float* Wq = (const float*)d_in[2];
    const float* Wk = (const float*)d_in[3];
    const float* Wv = (const float*)d_in[4];
    float* out = (float*)d_out;
    char* ws = (char*)d_ws;
    const size_t MB = 1u << 20;
    U16* Whi = (U16*)(ws);
    U16* Wlo = (U16*)(ws + 393216);
    U16* Qhi = (U16*)(ws + 1*MB);
    U16* Qlo = (U16*)(ws + 2*MB);
    U16* Khi = (U16*)(ws + 3*MB);
    U16* Klo = (U16*)(ws + 4*MB);
    U16* Vt  = (U16*)(ws + 5*MB);
    float* Opart = (float*)(ws + 6*MB);
    float* mpart = (float*)(ws + 22*MB);
    float* lpart = (float*)(ws + 22*MB + (1u<<18));

    prep_w<<<dim3(192), 256, 0, stream>>>(Wq, Wk, Wv, Whi, Wlo);
    qkv_kernel<<<dim3(256), 256, 0, stream>>>(x, Whi, Wlo, Qhi, Qlo, Khi, Klo, Vt);
    attn_kernel<<<dim3(NQT, B_, SPLITS), 256, 0, stream>>>(Qhi, Qlo, Khi, Klo, Vt, pad,
                                                           Opart, mpart, lpart);
    combine_kernel<<<dim3((B_*S_*H_)/256), 256, 0, stream>>>(Opart, mpart, lpart, Vt, out);
}

// Round 3
// 152.766 us; speedup vs baseline: 1.0758x; 1.0758x over previous
//
#include <hip/hip_runtime.h>
#include <hip/hip_bf16.h>
#include <math.h>

#define B_ 4
#define S_ 2048
#define E_ 1024
#define H_ 64
#define NQT 32          // S/64 q-tiles
#define SPLITS 8
#define TPS 4           // 64-key tiles per split (256 keys/split)
#define SENT (-1.25e8f) // masked-logit sentinel (= -1e9 * 0.125)

typedef short bf16x8 __attribute__((ext_vector_type(8)));
typedef float f32x4 __attribute__((ext_vector_type(4)));
typedef unsigned short U16;
typedef U16 u16x8 __attribute__((ext_vector_type(8)));
typedef U16 u16x4 __attribute__((ext_vector_type(4)));

__device__ __forceinline__ U16 f2bf(float f){
    unsigned u = __builtin_bit_cast(unsigned, f);
    u += 0x7fffu + ((u >> 16) & 1u);          // RNE
    return (U16)(u >> 16);
}
__device__ __forceinline__ float bf2f(U16 h){
    return __builtin_bit_cast(float, ((unsigned)h) << 16);
}
#define MFMA16(a,b,c) __builtin_amdgcn_mfma_f32_16x16x32_bf16((a),(b),(c),0,0,0)

typedef const __attribute__((address_space(1))) void GvPtr;
typedef __attribute__((address_space(3))) void LdsPtr;
__device__ __forceinline__ void gload_lds16(const void* g, void* l){
    __builtin_amdgcn_global_load_lds((GvPtr*)g, (LdsPtr*)l, 16, 0, 0);
}

// ---------------------------------------------------------------------------
// Kernel 0: split W (3 comps, fp32) into hi/lo bf16 pair arrays.
// ---------------------------------------------------------------------------
__global__ __launch_bounds__(256) void prep_w(
    const float* __restrict__ Wq, const float* __restrict__ Wk,
    const float* __restrict__ Wv, U16* __restrict__ Whi, U16* __restrict__ Wlo)
{
    int i4 = (blockIdx.x*256 + threadIdx.x) * 4;     // < 3*65536
    int c = i4 >> 16, rem = i4 & 65535;
    const float* src = (c==0) ? Wq : (c==1) ? Wk : Wv;
    float4 v = *(const float4*)(src + rem);
    float a[4] = {v.x, v.y, v.z, v.w};
    u16x4 hv, lv;
    #pragma unroll
    for (int j=0;j<4;j++){ U16 h = f2bf(a[j]); hv[j]=h; lv[j]=f2bf(a[j]-bf2f(h)); }
    *(u16x4*)(Whi + i4) = hv;
    *(u16x4*)(Wlo + i4) = lv;
}

// ---------------------------------------------------------------------------
// Kernel 1: fused QKV projection. Grid 256 x 512 thr (8 waves): waves 0-3
// handle k in [0,512), waves 4-7 k in [512,1024); wave (wv&3) -> 16-h slice.
// W frags from L2 with explicit next-iter reg prefetch; x staged hi/lo in
// double-buffered LDS; cross-k LDS reduce at end. 8 waves/CU for latency.
// ---------------------------------------------------------------------------
__global__ __launch_bounds__(512) void qkv_kernel(
    const float* __restrict__ x, const U16* __restrict__ Whi_g,
    const U16* __restrict__ Wlo_g,
    U16* __restrict__ Qhi, U16* __restrict__ Qlo,
    U16* __restrict__ Khi, U16* __restrict__ Klo, U16* __restrict__ Vt)
{
    __shared__ __align__(16) U16 XH[2][2][2048], XL[2][2][2048];  // [buf][khalf][32*64]
    __shared__ __align__(16) float Red[4*64*28];
    const int m0 = blockIdx.x * 32;
    const int tid = threadIdx.x, lane = tid & 63, wv = tid >> 6;
    const int l15 = lane & 15, quad = lane >> 4;
    const int hs = (wv & 3) * 16;      // this wave's h-slice
    const int kh = wv >> 2;            // k-half (0/1)
    const int p2 = tid >> 8;           // staging panel == k-half of staged data
    const int rr = (tid >> 3) & 31, ag = tid & 7;

    f32x4 acc[3][2];
    #pragma unroll
    for (int c=0;c<3;c++)
    #pragma unroll
    for (int mt=0;mt<2;mt++) acc[c][mt] = f32x4{0.f,0.f,0.f,0.f};

    const float* xrow = x + (size_t)(m0 + rr)*E_ + (size_t)p2*512 + ag*8;

    auto cvwrite = [&](int buf, float4 a, float4 b2){
        float vv[8] = {a.x,a.y,a.z,a.w,b2.x,b2.y,b2.z,b2.w};
        u16x8 hv, lv;
        #pragma unroll
        for (int j=0;j<8;j++){ U16 h = f2bf(vv[j]); hv[j]=h; lv[j]=f2bf(vv[j]-bf2f(h)); }
        const int idx = rr*8 + (ag ^ (rr & 7));      // XOR swizzle
        ((u16x8*)XH[buf][p2])[idx] = hv;
        ((u16x8*)XL[buf][p2])[idx] = lv;
    };

    const size_t wbase = (size_t)(hs + l15)*E_ + (size_t)kh*512 + quad*8;
    bf16x8 bhc[3][2], blc[3][2], bhn[3][2], bln[3][2];
    auto loadW = [&](int it, bf16x8 (*bh)[2], bf16x8 (*bl)[2]){
        #pragma unroll
        for (int c=0;c<3;c++)
        #pragma unroll
        for (int kk=0;kk<2;kk++){
            const size_t o = (size_t)c*65536 + wbase + it*64 + kk*32;
            bh[c][kk] = *(const bf16x8*)(Whi_g + o);
            bl[c][kk] = *(const bf16x8*)(Wlo_g + o);
        }
    };

    {   float4 xa = ((const float4*)xrow)[0], xb = ((const float4*)xrow)[1];
        cvwrite(0, xa, xb); }
    loadW(0, bhc, blc);
    __syncthreads();

    int p = 0;
    for (int it = 0; it < 8; ++it) {
        const bool have = (it < 7);
        float4 xa, xb;
        if (have) {
            const float* xs = xrow + (it+1)*64;
            xa = ((const float4*)xs)[0]; xb = ((const float4*)xs)[1];
            loadW(it+1, bhn, bln);                    // prefetch next W frags
        }
        #pragma unroll
        for (int kk=0;kk<2;kk++)
        #pragma unroll
        for (int mt=0;mt<2;mt++){
            const int row = mt*16 + l15;
            const int idx = row*8 + ((kk*4+quad) ^ (l15 & 7));
            bf16x8 ah = ((const bf16x8*)XH[p][kh])[idx];
            bf16x8 al = ((const bf16x8*)XL[p][kh])[idx];
            #pragma unroll
            for (int c=0;c<3;c++){
                acc[c][mt] = MFMA16(ah, bhc[c][kk], acc[c][mt]);  // hi*hi
                acc[c][mt] = MFMA16(ah, blc[c][kk], acc[c][mt]);  // hi*lo
                acc[c][mt] = MFMA16(al, bhc[c][kk], acc[c][mt]);  // lo*hi
            }
        }
        if (have) cvwrite(p^1, xa, xb);
        __syncthreads();
        if (have) {
            #pragma unroll
            for (int c=0;c<3;c++)
            #pragma unroll
            for (int kk=0;kk<2;kk++){ bhc[c][kk]=bhn[c][kk]; blc[c][kk]=bln[c][kk]; }
        }
        p ^= 1;
    }

    // cross-k-half reduce through LDS (stride 28 floats: 16B-aligned, even banks)
    if (kh == 1) {
        float* rp = &Red[((wv&3)*64 + lane)*28];
        #pragma unroll
        for (int c=0;c<3;c++)
        #pragma unroll
        for (int mt=0;mt<2;mt++)
            *(f32x4*)(rp + (c*2+mt)*4) = acc[c][mt];
    }
    __syncthreads();
    if (kh == 0) {
        const float* rp = &Red[((wv&3)*64 + lane)*28];
        #pragma unroll
        for (int c=0;c<3;c++)
        #pragma unroll
        for (int mt=0;mt<2;mt++)
            acc[c][mt] += *(const f32x4*)(rp + (c*2+mt)*4);

        const int h = hs + l15;
        #pragma unroll
        for (int mt=0;mt<2;mt++){
            const int row = m0 + mt*16 + quad*4;
            #pragma unroll
            for (int r=0;r<4;r++){
                float vq = acc[0][mt][r]; U16 hq = f2bf(vq);
                Qhi[(size_t)(row+r)*H_ + h] = hq;
                Qlo[(size_t)(row+r)*H_ + h] = f2bf(vq - bf2f(hq));
                float vk = acc[1][mt][r]; U16 hk = f2bf(vk);
                Khi[(size_t)(row+r)*H_ + h] = hk;
                Klo[(size_t)(row+r)*H_ + h] = f2bf(vk - bf2f(hk));
            }
            const int b = row >> 11, s0 = row & (S_-1);
            u16x4 pk;
            #pragma unroll
            for (int r=0;r<4;r++) pk[r] = f2bf(acc[2][mt][r]);
            *(u16x4*)(Vt + ((size_t)b*H_ + h)*S_ + s0) = pk;   // V^T [b][h][s]
        }
    }
}

// ---------------------------------------------------------------------------
// Kernel 2: flash attention, split-K, S^T form, double-buffered K/V staging.
// Source-permuted global_load_lds gives pre-swizzled LDS (even bank spread).
// ---------------------------------------------------------------------------
__global__ __launch_bounds__(256) void attn_kernel(
    const U16* __restrict__ Qhi, const U16* __restrict__ Qlo,
    const U16* __restrict__ Khi, const U16* __restrict__ Klo,
    const U16* __restrict__ Vt, const int* __restrict__ pad,
    float* __restrict__ Opart, float* __restrict__ mpart, float* __restrict__ lpart)
{
    const int qt = blockIdx.x, b = blockIdx.y, sp = blockIdx.z;
    const int t0 = sp * TPS;
    if (t0 > qt) return;
    const int t1 = min(t0 + TPS, qt + 1);

    __shared__ __align__(16) U16 KtH[2][64*64], KtL[2][64*64], Vts[2][64*64];
    __shared__ __align__(16) U16 Ps[4][16*80];   // per-wave P[q=16][key 64], stride 80

    const int tid = threadIdx.x, lane = tid & 63, wv = tid >> 6;
    const int l15 = lane & 15, quad = lane >> 4;

    auto stage = [&](int t, int bb){
        const int kb2 = t * 64;
        const U16* khp = Khi + ((size_t)b*S_ + kb2)*H_;
        const U16* klp = Klo + ((size_t)b*S_ + kb2)*H_;
        #pragma unroll
        for (int ch=0; ch<2; ++ch){
            const int sb = wv*128 + ch*64;
            const int u = sb + lane;
            const int row = u >> 3, g = u & 7, gs = g ^ (row & 7);   // source-permute
            gload_lds16(khp + (size_t)row*H_ + gs*8, KtH[bb] + sb*8);
            gload_lds16(klp + (size_t)row*H_ + gs*8, KtL[bb] + sb*8);
            gload_lds16(Vt + ((size_t)b*H_ + row)*S_ + kb2 + gs*8, Vts[bb] + sb*8);
        }
    };

    // Q fragments as B-operand (lane l15 = q-row, k = d = quad*8+j)
    const size_t qrow = (size_t)b*S_ + qt*64 + wv*16 + l15;
    bf16x8 aqh0 = *(const bf16x8*)(Qhi + qrow*H_ + quad*8);
    bf16x8 aqh1 = *(const bf16x8*)(Qhi + qrow*H_ + 32 + quad*8);
    bf16x8 aql0 = *(const bf16x8*)(Qlo + qrow*H_ + quad*8);
    bf16x8 aql1 = *(const bf16x8*)(Qlo + qrow*H_ + 32 + quad*8);

    float m_i = -INFINITY, l_i = 0.f;
    f32x4 o[4];
    #pragma unroll
    for (int i=0;i<4;i++) o[i] = f32x4{0.f,0.f,0.f,0.f};
    const int qg = qt*64 + wv*16 + l15;
    U16* Pw = &Ps[wv][0];

    stage(t0, 0);
    int pv = pad[(size_t)b*S_ + t0*64 + lane];

    int p = 0;
    for (int t = t0; t < t1; ++t, p ^= 1) {
        __syncthreads();                      // buf p staged (vmcnt drained) & prev reads done
        int pvn = 0;
        if (t + 1 < t1) {
            stage(t+1, p^1);                  // async; lands during compute below
            pvn = pad[(size_t)b*S_ + (t+1)*64 + lane];
        }
        const unsigned long long pm = __ballot(pv != 0);
        const int kb = t * 64;
        const int sw = l15 & 7;

        // --- S^T = K Q^T (hi/lo, fp32-accurate logits) ---
        f32x4 z[4];
        #pragma unroll
        for (int nt=0; nt<4; nt++){
            const int kr = (nt*16 + l15)*8;
            bf16x8 kh0 = ((const bf16x8*)KtH[p])[kr + (quad ^ sw)];
            bf16x8 kh1 = ((const bf16x8*)KtH[p])[kr + ((4+quad) ^ sw)];
            bf16x8 kl0 = ((const bf16x8*)KtL[p])[kr + (quad ^ sw)];
            bf16x8 kl1 = ((const bf16x8*)KtL[p])[kr + ((4+quad) ^ sw)];
            f32x4 zz = f32x4{0.f,0.f,0.f,0.f};
            zz = MFMA16(kh0, aqh0, zz);
            zz = MFMA16(kh1, aqh1, zz);
            zz = MFMA16(kh0, aql0, zz);
            zz = MFMA16(kh1, aql1, zz);
            zz = MFMA16(kl0, aqh0, zz);
            zz = MFMA16(kl1, aqh1, zz);
            z[nt] = zz;
        }
        // --- mask + scale ---
        float rmax = -INFINITY;
        #pragma unroll
        for (int nt=0; nt<4; nt++){
            const int rel = qg - kb - nt*16 - quad*4;
            const unsigned mb = (unsigned)(pm >> (nt*16 + quad*4)) & 0xFu;
            #pragma unroll
            for (int r=0;r<4;r++){
                const bool ok = (r <= rel) && ((mb >> r) & 1u);
                const float v = ok ? z[nt][r]*0.125f : SENT;
                z[nt][r] = v;
                rmax = fmaxf(rmax, v);
            }
        }
        rmax = fmaxf(rmax, __shfl_xor(rmax, 16));
        rmax = fmaxf(rmax, __shfl_xor(rmax, 32));
        const float mn = fmaxf(m_i, rmax);
        const float alpha = __expf(m_i - mn);
        m_i = mn;
        float rsum = 0.f;
        #pragma unroll
        for (int nt=0; nt<4; nt++)
        #pragma unroll
        for (int r=0;r<4;r++){
            const float pe = __expf(z[nt][r] - mn);
            z[nt][r] = pe;
            rsum += pe;
        }
        rsum += __shfl_xor(rsum, 16);
        rsum += __shfl_xor(rsum, 32);
        l_i = l_i*alpha + rsum;
        #pragma unroll
        for (int nt=0; nt<4; nt++)
        #pragma unroll
        for (int r=0;r<4;r++) o[nt][r] *= alpha;

        // --- P -> per-wave LDS row-major [q=l15][key] ---
        #pragma unroll
        for (int nt=0; nt<4; nt++){
            u16x4 pk;
            #pragma unroll
            for (int r=0;r<4;r++) pk[r] = f2bf(z[nt][r]);
            *(u16x4*)(Pw + l15*80 + nt*16 + quad*4) = pk;
        }
        // --- O^T += V^T P^T ---
        #pragma unroll
        for (int ks=0; ks<2; ks++){
            bf16x8 bp = *(const bf16x8*)(Pw + l15*80 + ks*32 + quad*8);
            #pragma unroll
            for (int nt=0; nt<4; nt++){
                bf16x8 av = ((const bf16x8*)Vts[p])[(nt*16 + l15)*8 + ((ks*4+quad) ^ sw)];
                o[nt] = MFMA16(av, bp, o[nt]);
            }
        }
        pv = pvn;
    }
    // partials: row = [b][qt][sp][q 64], cols h
    const size_t rbase = ((size_t)((b*NQT + qt)*SPLITS + sp))*64 + wv*16 + l15;
    if (quad == 0) { mpart[rbase] = m_i; lpart[rbase] = l_i; }
    #pragma unroll
    for (int nt=0; nt<4; nt++)
        *((f32x4*)(Opart + rbase*H_ + nt*16 + quad*4)) = o[nt];
}

// ---------------------------------------------------------------------------
// Kernel 3: merge split-K partials; inline mean-of-V for fully-masked rows.
// ---------------------------------------------------------------------------
__global__ __launch_bounds__(256) void combine_kernel(
    const float* __restrict__ Opart, const float* __restrict__ mpart,
    const float* __restrict__ lpart, const U16* __restrict__ Vt,
    float* __restrict__ out)
{
    const int idx = blockIdx.x*256 + threadIdx.x;
    const int h = idx & 63;
    const int q = (idx >> 6) & (S_-1);
    const int b = idx >> 17;
    const int qt = q >> 6, r = q & 63;
    const int ns = (qt >> 2) + 1;
    const size_t rb = ((size_t)(b*NQT + qt)*SPLITS)*64 + r;
    float M = -INFINITY;
    for (int s2=0; s2<ns; s2++) M = fmaxf(M, mpart[rb + (size_t)s2*64]);
    float res;
    if (M == SENT) {
        const U16* vsrc = Vt + ((size_t)b*H_ + h)*S_;
        float sm = 0.f;
        for (int s=0; s<S_; ++s) sm += bf2f(vsrc[s]);
        res = sm * (1.f/(float)S_);
    } else {
        float L = 0.f, accv = 0.f;
        for (int s2=0; s2<ns; s2++){
            const float mi = mpart[rb + (size_t)s2*64];
            const float w = __expf(mi - M);
            L    += w * lpart[rb + (size_t)s2*64];
            accv += w * Opart[(rb + (size_t)s2*64)*H_ + h];
        }
        res = accv / L;
    }
    out[idx] = res;
}

// ---------------------------------------------------------------------------
// Workspace: Whi 0 (384K) | Wlo 384K | Qhi 1M | Qlo 2M | Khi 3M | Klo 4M |
//            Vt 5M | Opart 6M (16M) | mpart 22M | lpart 22.25M
// ---------------------------------------------------------------------------
extern "C" void kernel_launch(void* const* d_in, const int* in_sizes, int n_in,
                              void* d_out, int out_size, void* d_ws, size_t ws_size,
                              hipStream_t stream)
{
    (void)in_sizes; (void)n_in; (void)out_size; (void)ws_size;
    const float* x  = (const float*)d_in[0];
    const int* pad  = (const int*)d_in[1];
    const float* Wq = (const float*)d_in[2];
    const float* Wk = (const float*)d_in[3];
    const float* Wv = (const float*)d_in[4];
    float* out = (float*)d_out;
    char* ws = (char*)d_ws;
    const size_t MB = 1u << 20;
    U16* Whi = (U16*)(ws);
    U16* Wlo = (U16*)(ws + 393216);
    U16* Qhi = (U16*)(ws + 1*MB);
    U16* Qlo = (U16*)(ws + 2*MB);
    U16* Khi = (U16*)(ws + 3*MB);
    U16* Klo = (U16*)(ws + 4*MB);
    U16* Vt  = (U16*)(ws + 5*MB);
    float* Opart = (float*)(ws + 6*MB);
    float* mpart = (float*)(ws + 22*MB);
    float* lpart = (float*)(ws + 22*MB + (1u<<18));

    prep_w<<<dim3(192), 256, 0, stream>>>(Wq, Wk, Wv, Whi, Wlo);
    qkv_kernel<<<dim3(256), 512, 0, stream>>>(x, Whi, Wlo, Qhi, Qlo, Khi, Klo, Vt);
    attn_kernel<<<dim3(NQT, B_, SPLITS), 256, 0, stream>>>(Qhi, Qlo, Khi, Klo, Vt, pad,
                                                           Opart, mpart, lpart);
    combine_kernel<<<dim3((B_*S_*H_)/256), 256, 0, stream>>>(Opart, mpart, lpart, Vt, out);
}